// Round 6
// baseline (1634.237 us; speedup 1.0000x reference)
//
#include <hip/hip_runtime.h>
#include <math.h>

#define NPTS 9216          // 96*96
#define CDIM 256
#define WW 96
#define W2 192
#define MACT (192*192)
#define BM 128
#define RB (NPTS / BM)     // 72 row/col blocks
#define NXCD 8
#define STRIPE (RB / NXCD) // 9

typedef __attribute__((ext_vector_type(8))) short short8;
typedef __attribute__((ext_vector_type(4))) float f32x4;

__device__ __forceinline__ void feed(float v, int i, float& v0, int& i0, float& v1, int& i1) {
    if (v > v0) { v1 = v0; i1 = i0; v0 = v; i0 = i; }
    else if (v > v1) { v1 = v; i1 = i; }
}

__device__ __forceinline__ unsigned short f2bf(float f) {
    unsigned u = __float_as_uint(f);
    unsigned r = (u + 0x7fffu + ((u >> 16) & 1u)) >> 16;
    return (unsigned short)r;
}
__device__ __forceinline__ float bf2f(unsigned short h) {
    return __uint_as_float(((unsigned)h) << 16);
}

__device__ __forceinline__ void gload16(const unsigned short* g, unsigned short* l) {
    __builtin_amdgcn_global_load_lds((const __attribute__((address_space(1))) unsigned int*)g,
                                     (__attribute__((address_space(3))) unsigned int*)l, 16, 0, 0);
}

// shared geometry macros (identifiers resolved in each kernel's scope)
#define TILE_SETUP \
    int bid = blockIdx.x; \
    int s = bid & 7; \
    int jj = bid >> 3; \
    int cb = jj / STRIPE; \
    int rb = s * STRIPE + (jj % STRIPE); \
    int p0 = rb * 128, q0 = cb * 128; \
    int t = threadIdx.x; \
    int lane = t & 63, w = t >> 6; \
    int wr = w >> 1, wc = w & 1; \
    int l15 = lane & 15, kslot = lane >> 4; \
    int srow = w * 16 + (lane >> 2); \
    int ssw = (srow >> 1) & 3; \
    int sgel = ((lane & 3) ^ ssw) * 8; \
    size_t gA0 = (size_t)(p0 + srow) * 256 + sgel; \
    size_t gA1 = gA0 + (size_t)64 * 256; \
    size_t gB0 = (size_t)(q0 + srow) * 256 + sgel; \
    size_t gB1 = gB0 + (size_t)64 * 256; \
    int lb0 = w * 512; \
    int lb1 = 2048 + w * 512;

#define STAGE(b, kc) { size_t ko = (size_t)(kc) * 32; int bb = (b) * 16384; \
        gload16(AhT + gA0 + ko, &lds[bb          + lb0]); \
        gload16(AhT + gA1 + ko, &lds[bb          + lb1]); \
        gload16(AlT + gA0 + ko, &lds[bb +  4096  + lb0]); \
        gload16(AlT + gA1 + ko, &lds[bb +  4096  + lb1]); \
        gload16(BhT + gB0 + ko, &lds[bb +  8192  + lb0]); \
        gload16(BhT + gB1 + ko, &lds[bb +  8192  + lb1]); \
        gload16(BlT + gB0 + ko, &lds[bb + 12288  + lb0]); \
        gload16(BlT + gB1 + ko, &lds[bb + 12288  + lb1]); }

#define FRAGS_AND_MFMA(bb) { \
        short8 ah[4], bh[4], xx[4]; \
        _Pragma("unroll") \
        for (int f = 0; f < 4; ++f) { int R = wr * 64 + f * 16 + l15; \
            ah[f] = *(const short8*)&lds[(bb) + R * 32 + ((kslot ^ ((R >> 1) & 3)) << 3)]; } \
        _Pragma("unroll") \
        for (int f = 0; f < 4; ++f) { int R = wc * 64 + f * 16 + l15; \
            bh[f] = *(const short8*)&lds[(bb) + 8192 + R * 32 + ((kslot ^ ((R >> 1) & 3)) << 3)]; } \
        _Pragma("unroll") \
        for (int i = 0; i < 4; ++i) _Pragma("unroll") for (int j2 = 0; j2 < 4; ++j2) \
            acc[i][j2] = __builtin_amdgcn_mfma_f32_16x16x32_bf16(ah[i], bh[j2], acc[i][j2], 0, 0, 0); \
        _Pragma("unroll") \
        for (int f = 0; f < 4; ++f) { int R = wc * 64 + f * 16 + l15; \
            xx[f] = *(const short8*)&lds[(bb) + 12288 + R * 32 + ((kslot ^ ((R >> 1) & 3)) << 3)]; } \
        _Pragma("unroll") \
        for (int i = 0; i < 4; ++i) _Pragma("unroll") for (int j2 = 0; j2 < 4; ++j2) \
            acc[i][j2] = __builtin_amdgcn_mfma_f32_16x16x32_bf16(ah[i], xx[j2], acc[i][j2], 0, 0, 0); \
        _Pragma("unroll") \
        for (int f = 0; f < 4; ++f) { int R = wr * 64 + f * 16 + l15; \
            xx[f] = *(const short8*)&lds[(bb) + 4096 + R * 32 + ((kslot ^ ((R >> 1) & 3)) << 3)]; } \
        _Pragma("unroll") \
        for (int i = 0; i < 4; ++i) _Pragma("unroll") for (int j2 = 0; j2 < 4; ++j2) \
            acc[i][j2] = __builtin_amdgcn_mfma_f32_16x16x32_bf16(xx[i], bh[j2], acc[i][j2], 0, 0, 0); }

__global__ void norm_inv_k(const float* __restrict__ src, float* __restrict__ inv) {
    int p = blockIdx.x * blockDim.x + threadIdx.x;
    if (p >= NPTS) return;
    float s = 0.f;
    for (int c = 0; c < CDIM; ++c) { float v = src[(size_t)c * NPTS + p]; s += v * v; }
    inv[p] = 1.0f / sqrtf(s);
}

__global__ __launch_bounds__(256) void prep_split_k(const float* __restrict__ src, const float* __restrict__ inv,
                                                    unsigned short* __restrict__ hiT, unsigned short* __restrict__ loT) {
    __shared__ float tile[64][65];
    int p0 = blockIdx.x * 64;
    int c0 = blockIdx.y * 64;
    int t = threadIdx.x;
    int cl = t >> 4, pl4 = (t & 15) * 4;
    #pragma unroll
    for (int i = 0; i < 4; ++i) {
        float4 v = *(const float4*)&src[(size_t)(c0 + i * 16 + cl) * NPTS + p0 + pl4];
        tile[i * 16 + cl][pl4] = v.x; tile[i * 16 + cl][pl4 + 1] = v.y;
        tile[i * 16 + cl][pl4 + 2] = v.z; tile[i * 16 + cl][pl4 + 3] = v.w;
    }
    __syncthreads();
    int pl = t >> 2, cs = t & 3;
    float iv = inv[p0 + pl];
    alignas(16) unsigned short hbuf[16], lbuf[16];
    #pragma unroll
    for (int j = 0; j < 16; ++j) {
        float v = tile[cs * 16 + j][pl] * iv;
        unsigned short h = f2bf(v);
        hbuf[j] = h;
        lbuf[j] = f2bf(v - bf2f(h));
    }
    size_t ob = (size_t)(p0 + pl) * 256 + c0 + cs * 16;
    *(uint4*)&hiT[ob] = *(const uint4*)&hbuf[0];
    *(uint4*)&hiT[ob + 8] = *(const uint4*)&hbuf[8];
    *(uint4*)&loT[ob] = *(const uint4*)&lbuf[0];
    *(uint4*)&loT[ob + 8] = *(const uint4*)&lbuf[8];
}

// ---------------- real sim kernel (unchanged from round 5) ----------------
__global__ __launch_bounds__(256) void sim_mfma_k(const unsigned short* __restrict__ AhT, const unsigned short* __restrict__ AlT,
                                                  const unsigned short* __restrict__ BhT, const unsigned short* __restrict__ BlT,
                                                  float4* __restrict__ prow, float4* __restrict__ pcol) {
    __shared__ __align__(16) unsigned short lds[32768];
    TILE_SETUP
    STAGE(0, 0);
    f32x4 acc[4][4];
    #pragma unroll
    for (int i = 0; i < 4; ++i)
        #pragma unroll
        for (int j2 = 0; j2 < 4; ++j2) acc[i][j2] = (f32x4){0.f, 0.f, 0.f, 0.f};
    __syncthreads();
    for (int kc = 0; kc < 8; ++kc) {
        if (kc < 7) STAGE((kc + 1) & 1, kc + 1);
        FRAGS_AND_MFMA((kc & 1) * 16384)
        __syncthreads();
    }
    float4* rowred = (float4*)lds;
    float4* colred = (float4*)lds + 256;
    #pragma unroll
    for (int f = 0; f < 4; ++f) {
        #pragma unroll
        for (int r = 0; r < 4; ++r) {
            float v0 = -3.0e38f, v1 = -3.0e38f; int i0 = 0, i1 = 0;
            #pragma unroll
            for (int fc = 0; fc < 4; ++fc)
                feed(acc[f][fc][r], q0 + wc * 64 + fc * 16 + l15, v0, i0, v1, i1);
            #pragma unroll
            for (int m = 1; m < 16; m <<= 1) {
                float pv0 = __shfl_xor(v0, m); int pi0 = __shfl_xor(i0, m);
                float pv1 = __shfl_xor(v1, m); int pi1 = __shfl_xor(i1, m);
                feed(pv0, pi0, v0, i0, v1, i1);
                feed(pv1, pi1, v0, i0, v1, i1);
            }
            if (l15 == 0) {
                int row = wr * 64 + f * 16 + kslot * 4 + r;
                rowred[row * 2 + wc] = make_float4(v0, v1, __int_as_float(i0), __int_as_float(i1));
            }
        }
    }
    #pragma unroll
    for (int fc = 0; fc < 4; ++fc) {
        float v0 = -3.0e38f, v1 = -3.0e38f; int i0 = 0, i1 = 0;
        #pragma unroll
        for (int f = 0; f < 4; ++f)
            #pragma unroll
            for (int r = 0; r < 4; ++r)
                feed(acc[f][fc][r], p0 + wr * 64 + f * 16 + kslot * 4 + r, v0, i0, v1, i1);
        #pragma unroll
        for (int m = 16; m < 64; m <<= 1) {
            float pv0 = __shfl_xor(v0, m); int pi0 = __shfl_xor(i0, m);
            float pv1 = __shfl_xor(v1, m); int pi1 = __shfl_xor(i1, m);
            feed(pv0, pi0, v0, i0, v1, i1);
            feed(pv1, pi1, v0, i0, v1, i1);
        }
        if (kslot == 0) {
            int col = wc * 64 + fc * 16 + l15;
            colred[col * 2 + wr] = make_float4(v0, v1, __int_as_float(i0), __int_as_float(i1));
        }
    }
    __syncthreads();
    if (t < 128) {
        float4 a = rowred[t * 2], b = rowred[t * 2 + 1];
        float v0 = a.x, v1 = a.y; int i0 = __float_as_int(a.z), i1 = __float_as_int(a.w);
        feed(b.x, __float_as_int(b.z), v0, i0, v1, i1);
        feed(b.y, __float_as_int(b.w), v0, i0, v1, i1);
        prow[(size_t)cb * NPTS + p0 + t] = make_float4(v0, v1, __int_as_float(i0), __int_as_float(i1));
        float4 c = colred[t * 2], d = colred[t * 2 + 1];
        v0 = c.x; v1 = c.y; i0 = __float_as_int(c.z); i1 = __float_as_int(c.w);
        feed(d.x, __float_as_int(d.z), v0, i0, v1, i1);
        feed(d.y, __float_as_int(d.w), v0, i0, v1, i1);
        pcol[(size_t)rb * NPTS + q0 + t] = make_float4(v0, v1, __int_as_float(i0), __int_as_float(i1));
    }
}

// ---------------- ablation kernels (scratch-only writes) ----------------
// A: staging + per-step barriers, nothing else
__global__ __launch_bounds__(256) void abl_stage_bar_k(const unsigned short* __restrict__ AhT, const unsigned short* __restrict__ AlT,
                                                       const unsigned short* __restrict__ BhT, const unsigned short* __restrict__ BlT,
                                                       float* __restrict__ scratch) {
    __shared__ __align__(16) unsigned short lds[32768];
    TILE_SETUP
    (void)wr; (void)wc; (void)l15; (void)kslot;
    STAGE(0, 0);
    __syncthreads();
    for (int kc = 0; kc < 8; ++kc) {
        if (kc < 7) STAGE((kc + 1) & 1, kc + 1);
        __syncthreads();
    }
    if (t == 0) scratch[bid] = (float)lds[0];
}

// B: all staging back-to-back, ONE final barrier
__global__ __launch_bounds__(256) void abl_stage_nobar_k(const unsigned short* __restrict__ AhT, const unsigned short* __restrict__ AlT,
                                                         const unsigned short* __restrict__ BhT, const unsigned short* __restrict__ BlT,
                                                         float* __restrict__ scratch) {
    __shared__ __align__(16) unsigned short lds[32768];
    TILE_SETUP
    (void)wr; (void)wc; (void)l15; (void)kslot;
    #pragma unroll
    for (int kc = 0; kc < 8; ++kc) STAGE(kc & 1, kc);
    __syncthreads();
    if (t == 0) scratch[bid] = (float)lds[0];
}

// C: stage once, then 8x (ds_read + 48 MFMA + barrier), no further staging
__global__ __launch_bounds__(256) void abl_comp_k(const unsigned short* __restrict__ AhT, const unsigned short* __restrict__ AlT,
                                                  const unsigned short* __restrict__ BhT, const unsigned short* __restrict__ BlT,
                                                  float* __restrict__ scratch) {
    __shared__ __align__(16) unsigned short lds[32768];
    TILE_SETUP
    STAGE(0, 0);
    STAGE(1, 1);
    f32x4 acc[4][4];
    #pragma unroll
    for (int i = 0; i < 4; ++i)
        #pragma unroll
        for (int j2 = 0; j2 < 4; ++j2) acc[i][j2] = (f32x4){0.f, 0.f, 0.f, 0.f};
    __syncthreads();
    for (int kc = 0; kc < 8; ++kc) {
        FRAGS_AND_MFMA((kc & 1) * 16384)
        __syncthreads();
    }
    float sacc = 0.f;
    #pragma unroll
    for (int i = 0; i < 4; ++i)
        #pragma unroll
        for (int j2 = 0; j2 < 4; ++j2)
            #pragma unroll
            for (int r = 0; r < 4; ++r) sacc += acc[i][j2][r];
    #pragma unroll
    for (int m = 1; m < 64; m <<= 1) sacc += __shfl_xor(sacc, m);
    if (lane == 0) scratch[bid * 4 + w] = sacc;
}

// D: full K-loop (staging + compute), lite epilogue
__global__ __launch_bounds__(256) void abl_noepi_k(const unsigned short* __restrict__ AhT, const unsigned short* __restrict__ AlT,
                                                   const unsigned short* __restrict__ BhT, const unsigned short* __restrict__ BlT,
                                                   float* __restrict__ scratch) {
    __shared__ __align__(16) unsigned short lds[32768];
    TILE_SETUP
    STAGE(0, 0);
    f32x4 acc[4][4];
    #pragma unroll
    for (int i = 0; i < 4; ++i)
        #pragma unroll
        for (int j2 = 0; j2 < 4; ++j2) acc[i][j2] = (f32x4){0.f, 0.f, 0.f, 0.f};
    __syncthreads();
    for (int kc = 0; kc < 8; ++kc) {
        if (kc < 7) STAGE((kc + 1) & 1, kc + 1);
        FRAGS_AND_MFMA((kc & 1) * 16384)
        __syncthreads();
    }
    float sacc = 0.f;
    #pragma unroll
    for (int i = 0; i < 4; ++i)
        #pragma unroll
        for (int j2 = 0; j2 < 4; ++j2)
            #pragma unroll
            for (int r = 0; r < 4; ++r) sacc += acc[i][j2][r];
    #pragma unroll
    for (int m = 1; m < 64; m <<= 1) sacc += __shfl_xor(sacc, m);
    if (lane == 0) scratch[bid * 4 + w] = sacc;
}

__global__ void merge_rows_k(const float4* __restrict__ prow, int* __restrict__ nn12,
                             float* __restrict__ msim, float* __restrict__ r12) {
    int p = blockIdx.x * blockDim.x + threadIdx.x;
    if (p >= NPTS) return;
    float v0 = -3.0e38f, v1 = -3.0e38f; int i0 = 0, i1 = 0;
    for (int c = 0; c < RB; ++c) {
        float4 s = prow[(size_t)c * NPTS + p];
        feed(s.x, __float_as_int(s.z), v0, i0, v1, i1);
        feed(s.y, __float_as_int(s.w), v0, i0, v1, i1);
    }
    nn12[p] = i0; msim[p] = v0;
    r12[p] = (2.0f - 2.0f * v0) / ((2.0f - 2.0f * v1) + 1e-8f);
}

__global__ void merge_cols_k(const float4* __restrict__ pcol, int* __restrict__ nn21, float* __restrict__ r21) {
    int q = blockIdx.x * blockDim.x + threadIdx.x;
    if (q >= NPTS) return;
    float v0 = -3.0e38f, v1 = -3.0e38f; int i0 = 0, i1 = 0;
    for (int k = 0; k < RB; ++k) {
        float4 s = pcol[(size_t)k * NPTS + q];
        feed(s.x, __float_as_int(s.z), v0, i0, v1, i1);
        feed(s.y, __float_as_int(s.w), v0, i0, v1, i1);
    }
    nn21[q] = i0;
    r21[q] = (2.0f - 2.0f * v0) / ((2.0f - 2.0f * v1) + 1e-8f);
}

__global__ void valid_k(const int* __restrict__ nn12, const float* __restrict__ r12,
                        const int* __restrict__ nn21, const float* __restrict__ r21,
                        int* __restrict__ validv) {
    int p = blockIdx.x * blockDim.x + threadIdx.x;
    if (p >= NPTS) return;
    int nn = nn12[p];
    bool mnn = (nn21[nn] == p) && (r12[p] <= 0.95f) && (r21[nn] <= 0.95f);
    int xA = p % WW, yA = p / WW, xB = nn % WW, yB = nn / WW;
    bool disc = (xA == 0) | (xA == WW - 1) | (yA == 0) | (yA == WW - 1) |
                (xB == 0) | (xB == WW - 1) | (yB == 0) | (yB == WW - 1);
    validv[p] = (mnn && !disc) ? 1 : 0;
}

__global__ __launch_bounds__(256) void refine_k(const float* __restrict__ actA, const float* __restrict__ actB,
                                                const int* __restrict__ nn12, const float* __restrict__ msim,
                                                const int* __restrict__ validv, float* __restrict__ out) {
    int n = blockIdx.x;
    int c = threadIdx.x;
    int val = validv[n];
    int nn = nn12[n];
    int xA = n % WW, yA = n / WW;
    int xB = nn % WW, yB = nn / WW;
    int pAx = val ? 2 * xA : 2, pAy = val ? 2 * yA : 2;
    int pBx = val ? 2 * xB : 2, pBy = val ? 2 * yB : 2;
    const int nxv[4] = {0, 0, 1, 1};
    const int nyv[4] = {0, 1, 0, 1};
    float a[4], b[4];
    #pragma unroll
    for (int i = 0; i < 4; ++i) {
        a[i] = actA[(size_t)c * MACT + (pAy + nyv[i]) * W2 + pAx + nxv[i]];
        b[i] = actB[(size_t)c * MACT + (pBy + nyv[i]) * W2 + pBx + nxv[i]];
    }
    float vals[24];
    #pragma unroll
    for (int i = 0; i < 4; ++i) vals[i] = a[i] * a[i];
    #pragma unroll
    for (int j = 0; j < 4; ++j) vals[4 + j] = b[j] * b[j];
    #pragma unroll
    for (int i = 0; i < 4; ++i)
        #pragma unroll
        for (int j = 0; j < 4; ++j) vals[8 + i * 4 + j] = a[i] * b[j];
    #pragma unroll
    for (int v = 0; v < 24; ++v) {
        float x = vals[v];
        #pragma unroll
        for (int m = 1; m < 64; m <<= 1) x += __shfl_xor(x, m);
        vals[v] = x;
    }
    __shared__ float part[24][4];
    __shared__ float fin[24];
    int wave = c >> 6, lane = c & 63;
    if (lane == 0) {
        #pragma unroll
        for (int v = 0; v < 24; ++v) part[v][wave] = vals[v];
    }
    __syncthreads();
    if (c < 24) fin[c] = part[c][0] + part[c][1] + part[c][2] + part[c][3];
    __syncthreads();
    if (c == 0) {
        float rsA[4], rsB[4], sc[4][4];
        #pragma unroll
        for (int i = 0; i < 4; ++i) rsA[i] = 1.0f / sqrtf(fin[i]);
        #pragma unroll
        for (int j = 0; j < 4; ++j) rsB[j] = 1.0f / sqrtf(fin[4 + j]);
        #pragma unroll
        for (int i = 0; i < 4; ++i)
            #pragma unroll
            for (int j = 0; j < 4; ++j) sc[i][j] = fin[8 + i * 4 + j] * rsA[i] * rsB[j];

        float ratA[4], scoreA[4]; int mAB[4];
        #pragma unroll
        for (int i = 0; i < 4; ++i) {
            float v0 = -3.0e38f, v1 = -3.0e38f; int i0 = 0, i1 = 0;
            #pragma unroll
            for (int j = 0; j < 4; ++j) feed(sc[i][j], j, v0, i0, v1, i1);
            float d0 = 2.0f - 2.0f * v0, d1 = 2.0f - 2.0f * v1;
            ratA[i] = d0 / (d1 + 1e-8f);
            scoreA[i] = d0; mAB[i] = i0;
        }
        float ratB[4]; int mBA[4];
        #pragma unroll
        for (int j = 0; j < 4; ++j) {
            float v0 = -3.0e38f, v1 = -3.0e38f; int i0 = 0, i1 = 0;
            #pragma unroll
            for (int i = 0; i < 4; ++i) feed(sc[i][j], i, v0, i0, v1, i1);
            float d0 = 2.0f - 2.0f * v0, d1 = 2.0f - 2.0f * v1;
            ratB[j] = d0 / (d1 + 1e-8f);
            mBA[j] = i0;
        }
        bool rm[4];
        #pragma unroll
        for (int i = 0; i < 4; ++i) {
            bool cyc = (mBA[mAB[i]] == i);
            rm[i] = (fmaxf(ratA[i], ratB[i]) < 0.9f) && cyc;
        }
        float sm[4];
        #pragma unroll
        for (int i = 0; i < 4; ++i) sm[i] = rm[i] ? scoreA[i] : 5.0f;
        {
            float v0 = -3.0e38f, v1 = -3.0e38f; int i0 = 0, i1 = 0;
            #pragma unroll
            for (int i = 0; i < 4; ++i) feed(sm[i], i, v0, i0, v1, i1);
            rm[i0] = false; rm[i1] = false;
        }
        out[n * 5 + 0] = msim[n];
        #pragma unroll
        for (int i = 0; i < 4; ++i) out[n * 5 + 1 + i] = sm[i];
        size_t b2 = (size_t)NPTS * 5;
        #pragma unroll
        for (int i = 0; i < 4; ++i) out[b2 + (size_t)n * 4 + i] = (float)(pAx + nxv[i]);
        #pragma unroll
        for (int i = 0; i < 4; ++i) out[b2 + (size_t)NPTS * 4 + (size_t)n * 4 + i] = (float)(pAy + nyv[i]);
        size_t b3 = b2 + (size_t)NPTS * 8;
        #pragma unroll
        for (int i = 0; i < 4; ++i) out[b3 + (size_t)n * 4 + i] = (float)(pBx + nxv[mAB[i]]);
        #pragma unroll
        for (int i = 0; i < 4; ++i) out[b3 + (size_t)NPTS * 4 + (size_t)n * 4 + i] = (float)(pBy + nyv[mAB[i]]);
        size_t b4 = b3 + (size_t)NPTS * 8;
        #pragma unroll
        for (int i = 0; i < 4; ++i) out[b4 + (size_t)n * 4 + i] = (rm[i] && val) ? 1.0f : 0.0f;
    }
}

extern "C" void kernel_launch(void* const* d_in, const int* in_sizes, int n_in,
                              void* d_out, int out_size, void* d_ws, size_t ws_size,
                              hipStream_t stream) {
    const float* mapA = (const float*)d_in[0];
    const float* mapB = (const float*)d_in[1];
    const float* actA = (const float*)d_in[2];
    const float* actB = (const float*)d_in[3];
    float* out = (float*)d_out;

    char* wsb = (char*)d_ws;
    size_t szT = (size_t)NPTS * 256 * sizeof(unsigned short);
    unsigned short* AhT = (unsigned short*)wsb;            wsb += szT;
    unsigned short* AlT = (unsigned short*)wsb;            wsb += szT;
    unsigned short* BhT = (unsigned short*)wsb;            wsb += szT;
    unsigned short* BlT = (unsigned short*)wsb;            wsb += szT;
    float4* prow = (float4*)wsb;                           wsb += (size_t)RB * NPTS * sizeof(float4);
    float4* pcol = (float4*)wsb;                           wsb += (size_t)RB * NPTS * sizeof(float4);
    float* invA = (float*)wsb;                             wsb += NPTS * sizeof(float);
    float* invB = (float*)wsb;                             wsb += NPTS * sizeof(float);
    int* nn12 = (int*)wsb;                                 wsb += NPTS * sizeof(int);
    float* msim = (float*)wsb;                             wsb += NPTS * sizeof(float);
    float* r12 = (float*)wsb;                              wsb += NPTS * sizeof(float);
    int* nn21 = (int*)wsb;                                 wsb += NPTS * sizeof(int);
    float* r21 = (float*)wsb;                              wsb += NPTS * sizeof(float);
    int* validv = (int*)wsb;                               wsb += NPTS * sizeof(int);
    float* ablscr = (float*)wsb;                           // 4 variants x RB*RB*4 floats (~332KB)

    norm_inv_k<<<NPTS / 256, 256, 0, stream>>>(mapA, invA);
    norm_inv_k<<<NPTS / 256, 256, 0, stream>>>(mapB, invB);
    dim3 gp(NPTS / 64, CDIM / 64);
    prep_split_k<<<gp, 256, 0, stream>>>(mapA, invA, AhT, AlT);
    prep_split_k<<<gp, 256, 0, stream>>>(mapB, invB, BhT, BlT);
    sim_mfma_k<<<RB * RB, 256, 0, stream>>>(AhT, AlT, BhT, BlT, prow, pcol);
    merge_rows_k<<<NPTS / 256, 256, 0, stream>>>(prow, nn12, msim, r12);
    merge_cols_k<<<NPTS / 256, 256, 0, stream>>>(pcol, nn21, r21);
    valid_k<<<NPTS / 256, 256, 0, stream>>>(nn12, r12, nn21, r21, validv);
    refine_k<<<NPTS, 256, 0, stream>>>(actA, actB, nn12, msim, validv, out);

    // ---- ablation probes (write only to scratch; outputs unaffected) ----
    int nb = RB * RB;
    abl_stage_bar_k<<<nb, 256, 0, stream>>>(AhT, AlT, BhT, BlT, ablscr);
    abl_stage_nobar_k<<<nb, 256, 0, stream>>>(AhT, AlT, BhT, BlT, ablscr + (size_t)nb * 4);
    abl_comp_k<<<nb, 256, 0, stream>>>(AhT, AlT, BhT, BlT, ablscr + (size_t)nb * 8);
    abl_noepi_k<<<nb, 256, 0, stream>>>(AhT, AlT, BhT, BlT, ablscr + (size_t)nb * 12);
}

// Round 7
// 836.715 us; speedup vs baseline: 1.9532x; 1.9532x over previous
//
#include <hip/hip_runtime.h>
#include <math.h>

#define NPTS 9216          // 96*96
#define CDIM 256
#define WW 96
#define W2 192
#define MACT (192*192)
#define BM 128
#define RB (NPTS / BM)     // 72 row/col blocks
#define NXCD 8
#define STRIPE (RB / NXCD) // 9

typedef __attribute__((ext_vector_type(8))) short short8;
typedef __attribute__((ext_vector_type(4))) float f32x4;

__device__ __forceinline__ void feed(float v, int i, float& v0, int& i0, float& v1, int& i1) {
    if (v > v0) { v1 = v0; i1 = i0; v0 = v; i0 = i; }
    else if (v > v1) { v1 = v; i1 = i; }
}

__device__ __forceinline__ unsigned short f2bf(float f) {
    unsigned u = __float_as_uint(f);
    unsigned r = (u + 0x7fffu + ((u >> 16) & 1u)) >> 16;
    return (unsigned short)r;
}
__device__ __forceinline__ float bf2f(unsigned short h) {
    return __uint_as_float(((unsigned)h) << 16);
}

__device__ __forceinline__ void gload16(const unsigned short* g, unsigned short* l) {
    __builtin_amdgcn_global_load_lds((const __attribute__((address_space(1))) unsigned int*)g,
                                     (__attribute__((address_space(3))) unsigned int*)l, 16, 0, 0);
}

__global__ void norm_inv_k(const float* __restrict__ src, float* __restrict__ inv) {
    int p = blockIdx.x * blockDim.x + threadIdx.x;
    if (p >= NPTS) return;
    float s = 0.f;
    for (int c = 0; c < CDIM; ++c) { float v = src[(size_t)c * NPTS + p]; s += v * v; }
    inv[p] = 1.0f / sqrtf(s);
}

__global__ __launch_bounds__(256) void prep_split_k(const float* __restrict__ src, const float* __restrict__ inv,
                                                    unsigned short* __restrict__ hiT, unsigned short* __restrict__ loT) {
    __shared__ float tile[64][65];
    int p0 = blockIdx.x * 64;
    int c0 = blockIdx.y * 64;
    int t = threadIdx.x;
    int cl = t >> 4, pl4 = (t & 15) * 4;
    #pragma unroll
    for (int i = 0; i < 4; ++i) {
        float4 v = *(const float4*)&src[(size_t)(c0 + i * 16 + cl) * NPTS + p0 + pl4];
        tile[i * 16 + cl][pl4] = v.x; tile[i * 16 + cl][pl4 + 1] = v.y;
        tile[i * 16 + cl][pl4 + 2] = v.z; tile[i * 16 + cl][pl4 + 3] = v.w;
    }
    __syncthreads();
    int pl = t >> 2, cs = t & 3;
    float iv = inv[p0 + pl];
    alignas(16) unsigned short hbuf[16], lbuf[16];
    #pragma unroll
    for (int j = 0; j < 16; ++j) {
        float v = tile[cs * 16 + j][pl] * iv;
        unsigned short h = f2bf(v);
        hbuf[j] = h;
        lbuf[j] = f2bf(v - bf2f(h));
    }
    size_t ob = (size_t)(p0 + pl) * 256 + c0 + cs * 16;
    *(uint4*)&hiT[ob] = *(const uint4*)&hbuf[0];
    *(uint4*)&hiT[ob + 8] = *(const uint4*)&hbuf[8];
    *(uint4*)&loT[ob] = *(const uint4*)&lbuf[0];
    *(uint4*)&loT[ob + 8] = *(const uint4*)&lbuf[8];
}

// sim tile GEMM: 128x128 per block, split-bf16 3-term MFMA, gload_lds dbuf,
// LDS-roundtrip top-2 epilogue (r6 ablation: old shuffle epilogue was 85% of time).
__global__ __launch_bounds__(256) void sim_mfma_k(const unsigned short* __restrict__ AhT, const unsigned short* __restrict__ AlT,
                                                  const unsigned short* __restrict__ BhT, const unsigned short* __restrict__ BlT,
                                                  float4* __restrict__ prow, float4* __restrict__ pcol) {
    __shared__ __align__(16) unsigned short lds[32768];   // 64KB

    int bid = blockIdx.x;
    int s = bid & 7;
    int jj = bid >> 3;
    int cb = jj / STRIPE;
    int rb = s * STRIPE + (jj % STRIPE);
    int p0 = rb * 128, q0 = cb * 128;
    int t = threadIdx.x;
    int lane = t & 63, w = t >> 6;
    int wr = w >> 1, wc = w & 1;
    int l15 = lane & 15, kslot = lane >> 4;

    int srow = w * 16 + (lane >> 2);
    int ssw = (srow >> 1) & 3;
    int sgel = ((lane & 3) ^ ssw) * 8;
    size_t gA0 = (size_t)(p0 + srow) * 256 + sgel;
    size_t gA1 = gA0 + (size_t)64 * 256;
    size_t gB0 = (size_t)(q0 + srow) * 256 + sgel;
    size_t gB1 = gB0 + (size_t)64 * 256;
    int lb0 = w * 512;
    int lb1 = 2048 + w * 512;

#define STAGE(b, kc) { size_t ko = (size_t)(kc) * 32; int bb = (b) * 16384; \
        gload16(AhT + gA0 + ko, &lds[bb          + lb0]); \
        gload16(AhT + gA1 + ko, &lds[bb          + lb1]); \
        gload16(AlT + gA0 + ko, &lds[bb +  4096  + lb0]); \
        gload16(AlT + gA1 + ko, &lds[bb +  4096  + lb1]); \
        gload16(BhT + gB0 + ko, &lds[bb +  8192  + lb0]); \
        gload16(BhT + gB1 + ko, &lds[bb +  8192  + lb1]); \
        gload16(BlT + gB0 + ko, &lds[bb + 12288  + lb0]); \
        gload16(BlT + gB1 + ko, &lds[bb + 12288  + lb1]); }

    STAGE(0, 0);

    f32x4 acc[4][4];
    #pragma unroll
    for (int i = 0; i < 4; ++i)
        #pragma unroll
        for (int j2 = 0; j2 < 4; ++j2) acc[i][j2] = (f32x4){0.f, 0.f, 0.f, 0.f};

    __syncthreads();

    for (int kc = 0; kc < 8; ++kc) {
        if (kc < 7) STAGE((kc + 1) & 1, kc + 1);
        int bb = (kc & 1) * 16384;
        short8 ah[4], bh[4], xx[4];
        #pragma unroll
        for (int f = 0; f < 4; ++f) {
            int R = wr * 64 + f * 16 + l15;
            ah[f] = *(const short8*)&lds[bb + R * 32 + ((kslot ^ ((R >> 1) & 3)) << 3)];
        }
        #pragma unroll
        for (int f = 0; f < 4; ++f) {
            int R = wc * 64 + f * 16 + l15;
            bh[f] = *(const short8*)&lds[bb + 8192 + R * 32 + ((kslot ^ ((R >> 1) & 3)) << 3)];
        }
        #pragma unroll
        for (int i = 0; i < 4; ++i)
            #pragma unroll
            for (int j2 = 0; j2 < 4; ++j2)
                acc[i][j2] = __builtin_amdgcn_mfma_f32_16x16x32_bf16(ah[i], bh[j2], acc[i][j2], 0, 0, 0);
        #pragma unroll
        for (int f = 0; f < 4; ++f) {
            int R = wc * 64 + f * 16 + l15;
            xx[f] = *(const short8*)&lds[bb + 12288 + R * 32 + ((kslot ^ ((R >> 1) & 3)) << 3)];
        }
        #pragma unroll
        for (int i = 0; i < 4; ++i)
            #pragma unroll
            for (int j2 = 0; j2 < 4; ++j2)
                acc[i][j2] = __builtin_amdgcn_mfma_f32_16x16x32_bf16(ah[i], xx[j2], acc[i][j2], 0, 0, 0);
        #pragma unroll
        for (int f = 0; f < 4; ++f) {
            int R = wr * 64 + f * 16 + l15;
            xx[f] = *(const short8*)&lds[bb + 4096 + R * 32 + ((kslot ^ ((R >> 1) & 3)) << 3)];
        }
        #pragma unroll
        for (int i = 0; i < 4; ++i)
            #pragma unroll
            for (int j2 = 0; j2 < 4; ++j2)
                acc[i][j2] = __builtin_amdgcn_mfma_f32_16x16x32_bf16(xx[i], bh[j2], acc[i][j2], 0, 0, 0);
        __syncthreads();
    }

    // ---- epilogue: dump acc to LDS (swizzled), then cheap serial top-2 ----
    // layout: lf[R*128 + pos*4 + (C&3)], pos = (C>>2) ^ (R&7)
    // write: 2-way bank conflict (free); row b128 reads + col b32 reads conflict-free/2-way.
    float* lf = (float*)lds;
    #pragma unroll
    for (int i = 0; i < 4; ++i)
        #pragma unroll
        for (int j2 = 0; j2 < 4; ++j2)
            #pragma unroll
            for (int r = 0; r < 4; ++r) {
                int R = wr * 64 + i * 16 + kslot * 4 + r;
                int C = wc * 64 + j2 * 16 + l15;
                lf[R * 128 + ((((C >> 2) ^ (R & 7)) << 2) | (C & 3))] = acc[i][j2][r];
            }
    __syncthreads();

    int Rr = t >> 1, hh = t & 1;       // thread: row Rr, col-half hh; also col Rr, row-half hh
    float rv0 = -3.0e38f, rv1 = -3.0e38f; int ri0 = 0, ri1 = 0;
    #pragma unroll
    for (int j = 0; j < 16; ++j) {
        int g = hh * 16 + j;           // real granule, ascending cols
        int pos = g ^ (Rr & 7);
        f32x4 v = *(const f32x4*)&lf[Rr * 128 + pos * 4];
        #pragma unroll
        for (int e = 0; e < 4; ++e) feed(v[e], q0 + g * 4 + e, rv0, ri0, rv1, ri1);
    }
    float cv0 = -3.0e38f, cv1 = -3.0e38f; int ci0 = 0, ci1 = 0;
    #pragma unroll 8
    for (int j = 0; j < 64; ++j) {
        int R = hh * 64 + j;           // ascending rows
        float v = lf[R * 128 + ((((Rr >> 2) ^ (R & 7)) << 2) | (Rr & 3))];
        feed(v, p0 + R, cv0, ci0, cv1, ci1);
    }
    __syncthreads();
    float4* hr = (float4*)lds;         // [256] row-half results
    float4* hc = (float4*)lds + 256;   // [256] col-half results
    hr[t] = make_float4(rv0, rv1, __int_as_float(ri0), __int_as_float(ri1));
    hc[t] = make_float4(cv0, cv1, __int_as_float(ci0), __int_as_float(ci1));
    __syncthreads();
    if (t < 128) {
        float4 a = hr[t * 2], b = hr[t * 2 + 1];
        float v0 = a.x, v1 = a.y; int i0 = __float_as_int(a.z), i1 = __float_as_int(a.w);
        feed(b.x, __float_as_int(b.z), v0, i0, v1, i1);
        feed(b.y, __float_as_int(b.w), v0, i0, v1, i1);
        prow[(size_t)cb * NPTS + p0 + t] = make_float4(v0, v1, __int_as_float(i0), __int_as_float(i1));
        float4 c = hc[t * 2], d = hc[t * 2 + 1];
        v0 = c.x; v1 = c.y; i0 = __float_as_int(c.z); i1 = __float_as_int(c.w);
        feed(d.x, __float_as_int(d.z), v0, i0, v1, i1);
        feed(d.y, __float_as_int(d.w), v0, i0, v1, i1);
        pcol[(size_t)rb * NPTS + q0 + t] = make_float4(v0, v1, __int_as_float(i0), __int_as_float(i1));
    }
#undef STAGE
}

__global__ void merge_rows_k(const float4* __restrict__ prow, int* __restrict__ nn12,
                             float* __restrict__ msim, float* __restrict__ r12) {
    int p = blockIdx.x * blockDim.x + threadIdx.x;
    if (p >= NPTS) return;
    float v0 = -3.0e38f, v1 = -3.0e38f; int i0 = 0, i1 = 0;
    for (int c = 0; c < RB; ++c) {
        float4 s = prow[(size_t)c * NPTS + p];
        feed(s.x, __float_as_int(s.z), v0, i0, v1, i1);
        feed(s.y, __float_as_int(s.w), v0, i0, v1, i1);
    }
    nn12[p] = i0; msim[p] = v0;
    r12[p] = (2.0f - 2.0f * v0) / ((2.0f - 2.0f * v1) + 1e-8f);
}

__global__ void merge_cols_k(const float4* __restrict__ pcol, int* __restrict__ nn21, float* __restrict__ r21) {
    int q = blockIdx.x * blockDim.x + threadIdx.x;
    if (q >= NPTS) return;
    float v0 = -3.0e38f, v1 = -3.0e38f; int i0 = 0, i1 = 0;
    for (int k = 0; k < RB; ++k) {
        float4 s = pcol[(size_t)k * NPTS + q];
        feed(s.x, __float_as_int(s.z), v0, i0, v1, i1);
        feed(s.y, __float_as_int(s.w), v0, i0, v1, i1);
    }
    nn21[q] = i0;
    r21[q] = (2.0f - 2.0f * v0) / ((2.0f - 2.0f * v1) + 1e-8f);
}

__global__ void valid_k(const int* __restrict__ nn12, const float* __restrict__ r12,
                        const int* __restrict__ nn21, const float* __restrict__ r21,
                        int* __restrict__ validv) {
    int p = blockIdx.x * blockDim.x + threadIdx.x;
    if (p >= NPTS) return;
    int nn = nn12[p];
    bool mnn = (nn21[nn] == p) && (r12[p] <= 0.95f) && (r21[nn] <= 0.95f);
    int xA = p % WW, yA = p / WW, xB = nn % WW, yB = nn / WW;
    bool disc = (xA == 0) | (xA == WW - 1) | (yA == 0) | (yA == WW - 1) |
                (xB == 0) | (xB == WW - 1) | (yB == 0) | (yB == WW - 1);
    validv[p] = (mnn && !disc) ? 1 : 0;
}

__global__ __launch_bounds__(256) void refine_k(const float* __restrict__ actA, const float* __restrict__ actB,
                                                const int* __restrict__ nn12, const float* __restrict__ msim,
                                                const int* __restrict__ validv, float* __restrict__ out) {
    int n = blockIdx.x;
    int c = threadIdx.x;
    int val = validv[n];
    int nn = nn12[n];
    int xA = n % WW, yA = n / WW;
    int xB = nn % WW, yB = nn / WW;
    int pAx = val ? 2 * xA : 2, pAy = val ? 2 * yA : 2;
    int pBx = val ? 2 * xB : 2, pBy = val ? 2 * yB : 2;
    const int nxv[4] = {0, 0, 1, 1};
    const int nyv[4] = {0, 1, 0, 1};
    float a[4], b[4];
    #pragma unroll
    for (int i = 0; i < 4; ++i) {
        a[i] = actA[(size_t)c * MACT + (pAy + nyv[i]) * W2 + pAx + nxv[i]];
        b[i] = actB[(size_t)c * MACT + (pBy + nyv[i]) * W2 + pBx + nxv[i]];
    }
    float vals[24];
    #pragma unroll
    for (int i = 0; i < 4; ++i) vals[i] = a[i] * a[i];
    #pragma unroll
    for (int j = 0; j < 4; ++j) vals[4 + j] = b[j] * b[j];
    #pragma unroll
    for (int i = 0; i < 4; ++i)
        #pragma unroll
        for (int j = 0; j < 4; ++j) vals[8 + i * 4 + j] = a[i] * b[j];
    #pragma unroll
    for (int v = 0; v < 24; ++v) {
        float x = vals[v];
        #pragma unroll
        for (int m = 1; m < 64; m <<= 1) x += __shfl_xor(x, m);
        vals[v] = x;
    }
    __shared__ float part[24][4];
    __shared__ float fin[24];
    int wave = c >> 6, lane = c & 63;
    if (lane == 0) {
        #pragma unroll
        for (int v = 0; v < 24; ++v) part[v][wave] = vals[v];
    }
    __syncthreads();
    if (c < 24) fin[c] = part[c][0] + part[c][1] + part[c][2] + part[c][3];
    __syncthreads();
    if (c == 0) {
        float rsA[4], rsB[4], sc[4][4];
        #pragma unroll
        for (int i = 0; i < 4; ++i) rsA[i] = 1.0f / sqrtf(fin[i]);
        #pragma unroll
        for (int j = 0; j < 4; ++j) rsB[j] = 1.0f / sqrtf(fin[4 + j]);
        #pragma unroll
        for (int i = 0; i < 4; ++i)
            #pragma unroll
            for (int j = 0; j < 4; ++j) sc[i][j] = fin[8 + i * 4 + j] * rsA[i] * rsB[j];

        float ratA[4], scoreA[4]; int mAB[4];
        #pragma unroll
        for (int i = 0; i < 4; ++i) {
            float v0 = -3.0e38f, v1 = -3.0e38f; int i0 = 0, i1 = 0;
            #pragma unroll
            for (int j = 0; j < 4; ++j) feed(sc[i][j], j, v0, i0, v1, i1);
            float d0 = 2.0f - 2.0f * v0, d1 = 2.0f - 2.0f * v1;
            ratA[i] = d0 / (d1 + 1e-8f);
            scoreA[i] = d0; mAB[i] = i0;
        }
        float ratB[4]; int mBA[4];
        #pragma unroll
        for (int j = 0; j < 4; ++j) {
            float v0 = -3.0e38f, v1 = -3.0e38f; int i0 = 0, i1 = 0;
            #pragma unroll
            for (int i = 0; i < 4; ++i) feed(sc[i][j], i, v0, i0, v1, i1);
            float d0 = 2.0f - 2.0f * v0, d1 = 2.0f - 2.0f * v1;
            ratB[j] = d0 / (d1 + 1e-8f);
            mBA[j] = i0;
        }
        bool rm[4];
        #pragma unroll
        for (int i = 0; i < 4; ++i) {
            bool cyc = (mBA[mAB[i]] == i);
            rm[i] = (fmaxf(ratA[i], ratB[i]) < 0.9f) && cyc;
        }
        float sm[4];
        #pragma unroll
        for (int i = 0; i < 4; ++i) sm[i] = rm[i] ? scoreA[i] : 5.0f;
        {
            float v0 = -3.0e38f, v1 = -3.0e38f; int i0 = 0, i1 = 0;
            #pragma unroll
            for (int i = 0; i < 4; ++i) feed(sm[i], i, v0, i0, v1, i1);
            rm[i0] = false; rm[i1] = false;
        }
        out[n * 5 + 0] = msim[n];
        #pragma unroll
        for (int i = 0; i < 4; ++i) out[n * 5 + 1 + i] = sm[i];
        size_t b2 = (size_t)NPTS * 5;
        #pragma unroll
        for (int i = 0; i < 4; ++i) out[b2 + (size_t)n * 4 + i] = (float)(pAx + nxv[i]);
        #pragma unroll
        for (int i = 0; i < 4; ++i) out[b2 + (size_t)NPTS * 4 + (size_t)n * 4 + i] = (float)(pAy + nyv[i]);
        size_t b3 = b2 + (size_t)NPTS * 8;
        #pragma unroll
        for (int i = 0; i < 4; ++i) out[b3 + (size_t)n * 4 + i] = (float)(pBx + nxv[mAB[i]]);
        #pragma unroll
        for (int i = 0; i < 4; ++i) out[b3 + (size_t)NPTS * 4 + (size_t)n * 4 + i] = (float)(pBy + nyv[mAB[i]]);
        size_t b4 = b3 + (size_t)NPTS * 8;
        #pragma unroll
        for (int i = 0; i < 4; ++i) out[b4 + (size_t)n * 4 + i] = (rm[i] && val) ? 1.0f : 0.0f;
    }
}

extern "C" void kernel_launch(void* const* d_in, const int* in_sizes, int n_in,
                              void* d_out, int out_size, void* d_ws, size_t ws_size,
                              hipStream_t stream) {
    const float* mapA = (const float*)d_in[0];
    const float* mapB = (const float*)d_in[1];
    const float* actA = (const float*)d_in[2];
    const float* actB = (const float*)d_in[3];
    float* out = (float*)d_out;

    char* wsb = (char*)d_ws;
    size_t szT = (size_t)NPTS * 256 * sizeof(unsigned short);
    unsigned short* AhT = (unsigned short*)wsb;            wsb += szT;
    unsigned short* AlT = (unsigned short*)wsb;            wsb += szT;
    unsigned short* BhT = (unsigned short*)wsb;            wsb += szT;
    unsigned short* BlT = (unsigned short*)wsb;            wsb += szT;
    float4* prow = (float4*)wsb;                           wsb += (size_t)RB * NPTS * sizeof(float4);
    float4* pcol = (float4*)wsb;                           wsb += (size_t)RB * NPTS * sizeof(float4);
    float* invA = (float*)wsb;                             wsb += NPTS * sizeof(float);
    float* invB = (float*)wsb;                             wsb += NPTS * sizeof(float);
    int* nn12 = (int*)wsb;                                 wsb += NPTS * sizeof(int);
    float* msim = (float*)wsb;                             wsb += NPTS * sizeof(float);
    float* r12 = (float*)wsb;                              wsb += NPTS * sizeof(float);
    int* nn21 = (int*)wsb;                                 wsb += NPTS * sizeof(int);
    float* r21 = (float*)wsb;                              wsb += NPTS * sizeof(float);
    int* validv = (int*)wsb;

    norm_inv_k<<<NPTS / 256, 256, 0, stream>>>(mapA, invA);
    norm_inv_k<<<NPTS / 256, 256, 0, stream>>>(mapB, invB);
    dim3 gp(NPTS / 64, CDIM / 64);
    prep_split_k<<<gp, 256, 0, stream>>>(mapA, invA, AhT, AlT);
    prep_split_k<<<gp, 256, 0, stream>>>(mapB, invB, BhT, BlT);
    sim_mfma_k<<<RB * RB, 256, 0, stream>>>(AhT, AlT, BhT, BlT, prow, pcol);
    merge_rows_k<<<NPTS / 256, 256, 0, stream>>>(prow, nn12, msim, r12);
    merge_cols_k<<<NPTS / 256, 256, 0, stream>>>(pcol, nn21, r21);
    valid_k<<<NPTS / 256, 256, 0, stream>>>(nn12, r12, nn21, r21, validv);
    refine_k<<<NPTS, 256, 0, stream>>>(actA, actB, nn12, msim, validv, out);
}